// Round 1
// baseline (748.604 us; speedup 1.0000x reference)
//
#include <hip/hip_runtime.h>

#define NEG_SLOPE 0.2f

constexpr int N_NODES = 50000;
constexpr int TPB = 256;
constexpr int SCAN_CHUNK = 1024;

// ---------------------------------------------------------------------------
// GEMM + fused alpha_src/alpha_dst epilogue.
// X: [n, K] row-major, W: [K, OUTD] row-major.
// Block handles ROWS rows. Thread t -> col = t % OUTD, row subgroup t / OUTD.
// The OUTD consecutive lanes covering one row are one wave (OUTD=64) or one
// half-wave (OUTD=32), so the row-dot h[r]·a is a shuffle reduction.
// ---------------------------------------------------------------------------
template <int K, int OUTD, int ROWS>
__global__ __launch_bounds__(TPB) void gemm_alpha(
    const float* __restrict__ X, const float* __restrict__ W,
    const float* __restrict__ avec_src, const float* __restrict__ avec_dst,
    float* __restrict__ Hout, float* __restrict__ as_out,
    float* __restrict__ ad_out, int n) {
  __shared__ float xs[ROWS][K];
  __shared__ float ws[K][OUTD];
  const int t = threadIdx.x;
  const int rowBase = blockIdx.x * ROWS;

  for (int i = t; i < K * OUTD; i += TPB) ws[i / OUTD][i % OUTD] = W[i];
  for (int i = t; i < ROWS * K; i += TPB) {
    int r = i / K, c = i % K;
    xs[r][c] = (rowBase + r < n) ? X[(size_t)(rowBase + r) * K + c] : 0.f;
  }
  __syncthreads();

  const int col = t % OUTD;
  const int rsub = t / OUTD;
  constexpr int RPI = TPB / OUTD;  // rows processed per sweep
  const float a_s = avec_src[col];
  const float a_d = avec_dst[col];

  for (int r0 = rsub; r0 < ROWS; r0 += RPI) {
    float acc = 0.f;
#pragma unroll
    for (int kk = 0; kk < K; ++kk) acc = fmaf(xs[r0][kk], ws[kk][col], acc);
    const int r = rowBase + r0;
    if (r < n) {  // uniform within the OUTD-lane group
      Hout[(size_t)r * OUTD + col] = acc;
      float vs = acc * a_s, vd = acc * a_d;
#pragma unroll
      for (int m = OUTD / 2; m >= 1; m >>= 1) {
        vs += __shfl_xor(vs, m);
        vd += __shfl_xor(vd, m);
      }
      if (col == 0) {
        as_out[r] = vs;
        ad_out[r] = vd;
      }
    }
  }
}

// ---------------------------------------------------------------------------
// CSR-by-dst build: count -> 3-phase exclusive scan -> permutation fill.
// Edge ids: [0,E) real edges, [E, E+N) self loops (id-E -> node).
// ---------------------------------------------------------------------------
__global__ void count_edges(const int* __restrict__ edst, int E, int n,
                            int* __restrict__ cnt) {
  int i = blockIdx.x * blockDim.x + threadIdx.x;
  if (i >= E + n) return;
  int d = (i < E) ? edst[i] : (i - E);
  atomicAdd(&cnt[d], 1);
}

__global__ void scan_block_sums(const int* __restrict__ in, int n,
                                int* __restrict__ sums) {
  __shared__ int sdata[TPB];
  const int base = blockIdx.x * SCAN_CHUNK;
  int s = 0;
  for (int i = threadIdx.x; i < SCAN_CHUNK; i += TPB) {
    int idx = base + i;
    s += (idx < n) ? in[idx] : 0;
  }
  sdata[threadIdx.x] = s;
  __syncthreads();
  for (int m = TPB / 2; m >= 1; m >>= 1) {
    if (threadIdx.x < m) sdata[threadIdx.x] += sdata[threadIdx.x + m];
    __syncthreads();
  }
  if (threadIdx.x == 0) sums[blockIdx.x] = sdata[0];
}

__global__ void scan_sums_exclusive(int* __restrict__ sums, int nchunks,
                                    int* __restrict__ total) {
  if (blockIdx.x == 0 && threadIdx.x == 0) {
    int run = 0;
    for (int i = 0; i < nchunks; ++i) {
      int v = sums[i];
      sums[i] = run;
      run += v;
    }
    *total = run;
  }
}

__global__ void scan_write(const int* __restrict__ in, int n,
                           const int* __restrict__ chunkOff,
                           const int* __restrict__ total,
                           int* __restrict__ rowoff) {
  __shared__ int tsum[TPB];
  const int base = blockIdx.x * SCAN_CHUNK;
  const int t = threadIdx.x;
  int v[4];
  int s = 0;
#pragma unroll
  for (int j = 0; j < 4; ++j) {
    int idx = base + t * 4 + j;
    v[j] = (idx < n) ? in[idx] : 0;
    s += v[j];
  }
  tsum[t] = s;
  __syncthreads();
  for (int off = 1; off < TPB; off <<= 1) {  // Hillis-Steele inclusive
    int x = (t >= off) ? tsum[t - off] : 0;
    __syncthreads();
    tsum[t] += x;
    __syncthreads();
  }
  int excl = ((t == 0) ? 0 : tsum[t - 1]) + chunkOff[blockIdx.x];
#pragma unroll
  for (int j = 0; j < 4; ++j) {
    int idx = base + t * 4 + j;
    if (idx < n) rowoff[idx] = excl;
    excl += v[j];
  }
  if (blockIdx.x == 0 && t == 0) rowoff[n] = *total;
}

__global__ void fill_perm(const int* __restrict__ edst, int E, int n,
                          int* __restrict__ cursor, int* __restrict__ perm) {
  int i = blockIdx.x * blockDim.x + threadIdx.x;
  if (i >= E + n) return;
  int d = (i < E) ? edst[i] : (i - E);
  int pos = atomicAdd(&cursor[d], 1);
  perm[pos] = i;
}

// ---------------------------------------------------------------------------
// GAT aggregation: one wave per destination node. Two sweeps over its edge
// list: (1) max of leaky(as[src]+ad[i]); (2) denom += exp(e-m) and
// acc[lane<D] += exp(e-m) * h[src][lane]. out = acc/denom + bias (opt. relu).
// ---------------------------------------------------------------------------
template <int D>
__global__ __launch_bounds__(TPB) void gat_aggregate(
    const float* __restrict__ Hf, const float* __restrict__ as,
    const float* __restrict__ ad, const int* __restrict__ rowoff,
    const int* __restrict__ perm, const int* __restrict__ esrc, int E, int n,
    const float* __restrict__ bias, float* __restrict__ out, int doRelu) {
  const int wave = (blockIdx.x * blockDim.x + threadIdx.x) >> 6;
  const int lane = threadIdx.x & 63;
  if (wave >= n) return;
  const int i = wave;
  const int beg = rowoff[i];
  const int end = rowoff[i + 1];
  const float adi = ad[i];

  float m = -1e30f;
  for (int k = beg; k < end; ++k) {
    int id = perm[k];
    int s = (id < E) ? esrc[id] : i;
    float e = as[s] + adi;
    e = (e > 0.f) ? e : e * NEG_SLOPE;
    m = fmaxf(m, e);
  }
  float denom = 0.f, acc = 0.f;
  for (int k = beg; k < end; ++k) {
    int id = perm[k];
    int s = (id < E) ? esrc[id] : i;
    float e = as[s] + adi;
    e = (e > 0.f) ? e : e * NEG_SLOPE;
    float w = __expf(e - m);
    denom += w;
    if (lane < D) acc = fmaf(w, Hf[(size_t)s * D + lane], acc);
  }
  if (lane < D) {
    float o = acc / denom + bias[lane];
    if (doRelu) o = fmaxf(o, 0.f);
    out[(size_t)i * D + lane] = o;
  }
}

// ---------------------------------------------------------------------------
// Decode: logits[g] = dot(z[src], z[dst]) over 32 dims. 32 lanes per edge.
// ---------------------------------------------------------------------------
__global__ __launch_bounds__(TPB) void decode_kernel(
    const float* __restrict__ z, const int* __restrict__ pos,
    const int* __restrict__ neg, int ED, float* __restrict__ out) {
  const int g = (blockIdx.x * blockDim.x + threadIdx.x) >> 5;
  const int lane = threadIdx.x & 31;
  if (g >= 2 * ED) return;
  int s, d;
  if (g < ED) {
    s = pos[g];
    d = pos[ED + g];
  } else {
    s = neg[g - ED];
    d = neg[ED + (g - ED)];
  }
  float v = z[(size_t)s * 32 + lane] * z[(size_t)d * 32 + lane];
#pragma unroll
  for (int m = 16; m >= 1; m >>= 1) v += __shfl_xor(v, m);
  if (lane == 0) out[g] = v;
}

// ---------------------------------------------------------------------------
extern "C" void kernel_launch(void* const* d_in, const int* in_sizes, int n_in,
                              void* d_out, int out_size, void* d_ws,
                              size_t ws_size, hipStream_t stream) {
  const int N = N_NODES;
  const float* x = (const float*)d_in[0];
  const int* ei = (const int*)d_in[1];
  const int* pe = (const int*)d_in[2];
  const int* ne = (const int*)d_in[3];
  const float* W1 = (const float*)d_in[4];
  const float* a_src1 = (const float*)d_in[5];
  const float* a_dst1 = (const float*)d_in[6];
  const float* b1 = (const float*)d_in[7];
  const float* W2 = (const float*)d_in[8];
  const float* a_src2 = (const float*)d_in[9];
  const float* a_dst2 = (const float*)d_in[10];
  const float* b2 = (const float*)d_in[11];
  float* out = (float*)d_out;

  const int E = in_sizes[1] / 2;
  const int ED = in_sizes[2] / 2;
  const int* esrc = ei;
  const int* edst = ei + E;

  // workspace carve-out (256B aligned)
  char* base = (char*)d_ws;
  size_t off = 0;
  auto alloc = [&](size_t bytes) {
    char* p = base + off;
    off = (off + bytes + 255) & ~(size_t)255;
    return p;
  };
  float* A = (float*)alloc((size_t)N * 64 * 4);       // h1, later h2
  float* B = (float*)alloc((size_t)N * 64 * 4);       // out1, later z
  float* as1 = (float*)alloc((size_t)N * 4);
  float* ad1 = (float*)alloc((size_t)N * 4);
  float* as2 = (float*)alloc((size_t)N * 4);
  float* ad2 = (float*)alloc((size_t)N * 4);
  int* cnt = (int*)alloc((size_t)N * 4);              // counts, then cursor
  int* rowoff = (int*)alloc((size_t)(N + 1) * 4);
  int* chunkSums = (int*)alloc(64 * 4);
  int* total = (int*)alloc(4);
  int* perm = (int*)alloc((size_t)(E + N) * 4);

  const int nEdgesTot = E + N;
  const int edgeBlocks = (nEdgesTot + TPB - 1) / TPB;
  const int nchunks = (N + SCAN_CHUNK - 1) / SCAN_CHUNK;

  // --- CSR build ---
  hipMemsetAsync(cnt, 0, (size_t)N * 4, stream);
  count_edges<<<edgeBlocks, TPB, 0, stream>>>(edst, E, N, cnt);
  scan_block_sums<<<nchunks, TPB, 0, stream>>>(cnt, N, chunkSums);
  scan_sums_exclusive<<<1, 64, 0, stream>>>(chunkSums, nchunks, total);
  scan_write<<<nchunks, TPB, 0, stream>>>(cnt, N, chunkSums, total, rowoff);
  hipMemcpyAsync(cnt, rowoff, (size_t)N * 4, hipMemcpyDeviceToDevice, stream);
  fill_perm<<<edgeBlocks, TPB, 0, stream>>>(edst, E, N, cnt, perm);

  // --- layer 1: h1 = x@W1 (+alpha dots), aggregate (+b1, relu) ---
  gemm_alpha<128, 64, 32><<<(N + 31) / 32, TPB, 0, stream>>>(
      x, W1, a_src1, a_dst1, A, as1, ad1, N);
  gat_aggregate<64><<<(N + 3) / 4, TPB, 0, stream>>>(
      A, as1, ad1, rowoff, perm, esrc, E, N, b1, B, 1);

  // --- layer 2: h2 = out1@W2 (+alpha dots), aggregate (+b2) ---
  gemm_alpha<64, 32, 64><<<(N + 63) / 64, TPB, 0, stream>>>(
      B, W2, a_src2, a_dst2, A, as2, ad2, N);
  gat_aggregate<32><<<(N + 3) / 4, TPB, 0, stream>>>(
      A, as2, ad2, rowoff, perm, esrc, E, N, b2, B, 0);

  // --- decode ---
  const long long decThreads = 2LL * ED * 32;
  decode_kernel<<<(int)((decThreads + TPB - 1) / TPB), TPB, 0, stream>>>(
      B, pe, ne, ED, out);
}

// Round 2
// 336.309 us; speedup vs baseline: 2.2259x; 2.2259x over previous
//
#include <hip/hip_runtime.h>

#define NEG_SLOPE 0.2f

constexpr int N_NODES = 50000;
constexpr int TPB = 256;
constexpr int SCAN_CHUNK = 1024;

// ---------------------------------------------------------------------------
// GEMM + fused alpha_src/alpha_dst epilogue.
// X: [n, K] row-major, W: [K, OUTD] row-major.
// Thread t -> col = t % OUTD, row subgroup t / OUTD; each thread accumulates
// 4 consecutive rows per sweep (register tiling: 1 ws read per 4 FMAs).
// xs padded (+1) so the 4 row-subgroups hit distinct LDS banks.
// ---------------------------------------------------------------------------
template <int K, int OUTD, int ROWS>
__global__ __launch_bounds__(TPB) void gemm_alpha(
    const float* __restrict__ X, const float* __restrict__ W,
    const float* __restrict__ avec_src, const float* __restrict__ avec_dst,
    float* __restrict__ Hout, float* __restrict__ as_out,
    float* __restrict__ ad_out, int n) {
  __shared__ float xs[ROWS][K + 1];
  __shared__ float ws[K][OUTD];
  const int t = threadIdx.x;
  const int rowBase = blockIdx.x * ROWS;

  for (int i = t; i < K * OUTD; i += TPB) ws[i / OUTD][i % OUTD] = W[i];
  for (int i = t; i < ROWS * K; i += TPB) {
    int r = i / K, c = i % K;
    xs[r][c] = (rowBase + r < n) ? X[(size_t)(rowBase + r) * K + c] : 0.f;
  }
  __syncthreads();

  const int col = t % OUTD;
  const int rsub = t / OUTD;
  constexpr int RPI = TPB / OUTD;  // row subgroups
  const float a_s = avec_src[col];
  const float a_d = avec_dst[col];

  for (int rb = 0; rb < ROWS; rb += RPI * 4) {
    const int r0 = rb + rsub * 4;  // this thread's 4 rows
    float acc[4] = {0.f, 0.f, 0.f, 0.f};
    for (int kk = 0; kk < K; ++kk) {
      float w = ws[kk][col];
#pragma unroll
      for (int q = 0; q < 4; ++q) acc[q] = fmaf(xs[r0 + q][kk], w, acc[q]);
    }
#pragma unroll
    for (int q = 0; q < 4; ++q) {
      const int r = rowBase + r0 + q;
      if (r < n) {  // uniform within the OUTD-lane group
        Hout[(size_t)r * OUTD + col] = acc[q];
        float vs = acc[q] * a_s, vd = acc[q] * a_d;
#pragma unroll
        for (int m = OUTD / 2; m >= 1; m >>= 1) {
          vs += __shfl_xor(vs, m);
          vd += __shfl_xor(vd, m);
        }
        if (col == 0) {
          as_out[r] = vs;
          ad_out[r] = vd;
        }
      }
    }
  }
}

// ---------------------------------------------------------------------------
// CSR-by-dst build: count -> 3-phase exclusive scan -> fill (stores SRC
// node id directly, resolving the perm->esrc indirection once).
// ---------------------------------------------------------------------------
__global__ void count_edges(const int* __restrict__ edst, int E, int n,
                            int* __restrict__ cnt) {
  int i = blockIdx.x * blockDim.x + threadIdx.x;
  if (i >= E + n) return;
  int d = (i < E) ? edst[i] : (i - E);
  atomicAdd(&cnt[d], 1);
}

__global__ void scan_block_sums(const int* __restrict__ in, int n,
                                int* __restrict__ sums) {
  __shared__ int sdata[TPB];
  const int base = blockIdx.x * SCAN_CHUNK;
  int s = 0;
  for (int i = threadIdx.x; i < SCAN_CHUNK; i += TPB) {
    int idx = base + i;
    s += (idx < n) ? in[idx] : 0;
  }
  sdata[threadIdx.x] = s;
  __syncthreads();
  for (int m = TPB / 2; m >= 1; m >>= 1) {
    if (threadIdx.x < m) sdata[threadIdx.x] += sdata[threadIdx.x + m];
    __syncthreads();
  }
  if (threadIdx.x == 0) sums[blockIdx.x] = sdata[0];
}

__global__ void scan_sums_exclusive(int* __restrict__ sums, int nchunks,
                                    int* __restrict__ total) {
  if (blockIdx.x == 0 && threadIdx.x == 0) {
    int run = 0;
    for (int i = 0; i < nchunks; ++i) {
      int v = sums[i];
      sums[i] = run;
      run += v;
    }
    *total = run;
  }
}

__global__ void scan_write(const int* __restrict__ in, int n,
                           const int* __restrict__ chunkOff,
                           const int* __restrict__ total,
                           int* __restrict__ rowoff) {
  __shared__ int tsum[TPB];
  const int base = blockIdx.x * SCAN_CHUNK;
  const int t = threadIdx.x;
  int v[4];
  int s = 0;
#pragma unroll
  for (int j = 0; j < 4; ++j) {
    int idx = base + t * 4 + j;
    v[j] = (idx < n) ? in[idx] : 0;
    s += v[j];
  }
  tsum[t] = s;
  __syncthreads();
  for (int off = 1; off < TPB; off <<= 1) {  // Hillis-Steele inclusive
    int x = (t >= off) ? tsum[t - off] : 0;
    __syncthreads();
    tsum[t] += x;
    __syncthreads();
  }
  int excl = ((t == 0) ? 0 : tsum[t - 1]) + chunkOff[blockIdx.x];
#pragma unroll
  for (int j = 0; j < 4; ++j) {
    int idx = base + t * 4 + j;
    if (idx < n) rowoff[idx] = excl;
    excl += v[j];
  }
  if (blockIdx.x == 0 && t == 0) rowoff[n] = *total;
}

__global__ void fill_psrc(const int* __restrict__ esrc,
                          const int* __restrict__ edst, int E, int n,
                          int* __restrict__ cursor, int* __restrict__ psrc) {
  int i = blockIdx.x * blockDim.x + threadIdx.x;
  if (i >= E + n) return;
  int d, s;
  if (i < E) {
    d = edst[i];
    s = esrc[i];
  } else {
    d = i - E;
    s = i - E;
  }
  int pos = atomicAdd(&cursor[d], 1);
  psrc[pos] = s;
}

// ---------------------------------------------------------------------------
// GAT aggregation: one wave per destination node, single pass (online
// softmax). Chunk of 64 edges: lane l owns edge beg+c+l -> parallel gathers
// of as[psrc]; wave-reduce max & sum; then broadcast (w, src) per edge via
// shfl while lanes cover feature dims. For D=32 the two half-waves process
// two edges per step; combined by one shfl_xor(32) at the end.
// ---------------------------------------------------------------------------
template <int D>
__global__ __launch_bounds__(TPB) void gat_aggregate(
    const float* __restrict__ Hf, const float* __restrict__ as,
    const float* __restrict__ ad, const int* __restrict__ rowoff,
    const int* __restrict__ psrc, int n, const float* __restrict__ bias,
    float* __restrict__ out, int doRelu) {
  const int wave = (blockIdx.x * blockDim.x + threadIdx.x) >> 6;
  const int lane = threadIdx.x & 63;
  if (wave >= n) return;
  const int i = wave;
  const int beg = rowoff[i];
  const int end = rowoff[i + 1];
  const float adi = ad[i];

  constexpr int EPI = 64 / D;          // edges per j-step (1 or 2)
  const int sub = (D < 64) ? (lane >> 5) : 0;  // which half-wave
  const int fl = lane & (D - 1);       // feature lane

  float m = -1e30f, denom = 0.f, acc = 0.f;

  for (int c = beg; c < end; c += 64) {
    const int k = c + lane;
    const bool valid = (k < end);
    int s = 0;
    float e = -1e30f;
    if (valid) {
      s = psrc[k];
      e = as[s] + adi;
      e = (e > 0.f) ? e : e * NEG_SLOPE;
    }
    // chunk max over the wave
    float cm = e;
#pragma unroll
    for (int mm = 32; mm >= 1; mm >>= 1) cm = fmaxf(cm, __shfl_xor(cm, mm));
    const float nm = fmaxf(m, cm);
    const float scale = __expf(m - nm);  // first chunk: exp(-1e30)=0
    const float w = valid ? __expf(e - nm) : 0.f;
    float ws = w;
#pragma unroll
    for (int mm = 32; mm >= 1; mm >>= 1) ws += __shfl_xor(ws, mm);
    denom = denom * scale + ws;
    acc *= scale;
    m = nm;

    const int cnt = min(64, end - c);
    for (int j = 0; j < cnt; j += EPI) {
      const int jj = j + sub;                     // <= 63 always
      const float wj = __shfl(w, jj);             // 0 for jj >= cnt
      const int sj = __shfl(s, jj);
      acc = fmaf(wj, Hf[(size_t)sj * D + fl], acc);
    }
  }
  if (D < 64) acc += __shfl_xor(acc, 32);
  if (lane < D) {
    float o = acc / denom + bias[lane];
    if (doRelu) o = fmaxf(o, 0.f);
    out[(size_t)i * D + lane] = o;
  }
}

// ---------------------------------------------------------------------------
// Decode: logits[g] = dot(z[src], z[dst]) over 32 dims.
// 8 lanes per edge, float4 per lane (coalesced 128B per row).
// ---------------------------------------------------------------------------
__global__ __launch_bounds__(TPB) void decode_kernel(
    const float* __restrict__ z, const int* __restrict__ pos,
    const int* __restrict__ neg, int ED, float* __restrict__ out) {
  const int g = (blockIdx.x * blockDim.x + threadIdx.x) >> 3;
  const int lane = threadIdx.x & 7;
  if (g >= 2 * ED) return;
  int s, d;
  if (g < ED) {
    s = pos[g];
    d = pos[ED + g];
  } else {
    s = neg[g - ED];
    d = neg[ED + (g - ED)];
  }
  const float4 a = ((const float4*)(z + (size_t)s * 32))[lane];
  const float4 b = ((const float4*)(z + (size_t)d * 32))[lane];
  float v = a.x * b.x + a.y * b.y + a.z * b.z + a.w * b.w;
#pragma unroll
  for (int mm = 4; mm >= 1; mm >>= 1) v += __shfl_xor(v, mm);
  if (lane == 0) out[g] = v;
}

// ---------------------------------------------------------------------------
extern "C" void kernel_launch(void* const* d_in, const int* in_sizes, int n_in,
                              void* d_out, int out_size, void* d_ws,
                              size_t ws_size, hipStream_t stream) {
  const int N = N_NODES;
  const float* x = (const float*)d_in[0];
  const int* ei = (const int*)d_in[1];
  const int* pe = (const int*)d_in[2];
  const int* ne = (const int*)d_in[3];
  const float* W1 = (const float*)d_in[4];
  const float* a_src1 = (const float*)d_in[5];
  const float* a_dst1 = (const float*)d_in[6];
  const float* b1 = (const float*)d_in[7];
  const float* W2 = (const float*)d_in[8];
  const float* a_src2 = (const float*)d_in[9];
  const float* a_dst2 = (const float*)d_in[10];
  const float* b2 = (const float*)d_in[11];
  float* out = (float*)d_out;

  const int E = in_sizes[1] / 2;
  const int ED = in_sizes[2] / 2;
  const int* esrc = ei;
  const int* edst = ei + E;

  // workspace carve-out (256B aligned)
  char* base = (char*)d_ws;
  size_t off = 0;
  auto alloc = [&](size_t bytes) {
    char* p = base + off;
    off = (off + bytes + 255) & ~(size_t)255;
    return p;
  };
  float* A = (float*)alloc((size_t)N * 64 * 4);  // h1, later h2
  float* B = (float*)alloc((size_t)N * 64 * 4);  // out1, later z
  float* as1 = (float*)alloc((size_t)N * 4);
  float* ad1 = (float*)alloc((size_t)N * 4);
  float* as2 = (float*)alloc((size_t)N * 4);
  float* ad2 = (float*)alloc((size_t)N * 4);
  int* cnt = (int*)alloc((size_t)N * 4);  // counts, then cursor
  int* rowoff = (int*)alloc((size_t)(N + 1) * 4);
  int* chunkSums = (int*)alloc(64 * 4);
  int* total = (int*)alloc(4);
  int* psrc = (int*)alloc((size_t)(E + N) * 4);

  const int nEdgesTot = E + N;
  const int edgeBlocks = (nEdgesTot + TPB - 1) / TPB;
  const int nchunks = (N + SCAN_CHUNK - 1) / SCAN_CHUNK;

  // --- CSR build (shared by both layers) ---
  hipMemsetAsync(cnt, 0, (size_t)N * 4, stream);
  count_edges<<<edgeBlocks, TPB, 0, stream>>>(edst, E, N, cnt);
  scan_block_sums<<<nchunks, TPB, 0, stream>>>(cnt, N, chunkSums);
  scan_sums_exclusive<<<1, 64, 0, stream>>>(chunkSums, nchunks, total);
  scan_write<<<nchunks, TPB, 0, stream>>>(cnt, N, chunkSums, total, rowoff);
  hipMemcpyAsync(cnt, rowoff, (size_t)N * 4, hipMemcpyDeviceToDevice, stream);
  fill_psrc<<<edgeBlocks, TPB, 0, stream>>>(esrc, edst, E, N, cnt, psrc);

  // --- layer 1: h1 = x@W1 (+alpha dots), aggregate (+b1, relu) ---
  gemm_alpha<128, 64, 32><<<(N + 31) / 32, TPB, 0, stream>>>(
      x, W1, a_src1, a_dst1, A, as1, ad1, N);
  gat_aggregate<64><<<(N + 3) / 4, TPB, 0, stream>>>(A, as1, ad1, rowoff, psrc,
                                                     N, b1, B, 1);

  // --- layer 2: h2 = out1@W2 (+alpha dots), aggregate (+b2) ---
  gemm_alpha<64, 32, 64><<<(N + 63) / 64, TPB, 0, stream>>>(
      B, W2, a_src2, a_dst2, A, as2, ad2, N);
  gat_aggregate<32><<<(N + 3) / 4, TPB, 0, stream>>>(A, as2, ad2, rowoff, psrc,
                                                     N, b2, B, 0);

  // --- decode ---
  const long long decThreads = 2LL * ED * 8;
  decode_kernel<<<(int)((decThreads + TPB - 1) / TPB), TPB, 0, stream>>>(
      B, pe, ne, ED, out);
}

// Round 3
// 277.114 us; speedup vs baseline: 2.7014x; 1.2136x over previous
//
#include <hip/hip_runtime.h>

#define NEG_SLOPE 0.2f

constexpr int N_NODES = 50000;
constexpr int TPB = 256;
constexpr int SCAN_CHUNK = 1024;

// ---------------------------------------------------------------------------
// GEMM + fused alpha_src/alpha_dst epilogue.
// X: [n, K] row-major, W: [K, OUTD] row-major.
// Only W is staged in LDS (as float4 over k: ws4[k4*OUTD+col], so lanes read
// at 16B stride = ideal ds_read_b128). X is read directly: all OUTD lanes of
// a row-group load the same address -> hardware broadcast, no staging needed.
// Each thread register-tiles RPT=4 rows.
// ---------------------------------------------------------------------------
template <int K, int OUTD, int RPT>
__global__ __launch_bounds__(TPB) void gemm_alpha(
    const float* __restrict__ X, const float* __restrict__ W,
    const float* __restrict__ avec_src, const float* __restrict__ avec_dst,
    float* __restrict__ Hout, float* __restrict__ as_out,
    float* __restrict__ ad_out, int n) {
  __shared__ float4 ws4[(K / 4) * OUTD];
  const int t = threadIdx.x;
  for (int i = t; i < (K / 4) * OUTD; i += TPB) {
    const int k4 = i / OUTD, c = i % OUTD;
    ws4[i] = make_float4(W[(4 * k4 + 0) * OUTD + c], W[(4 * k4 + 1) * OUTD + c],
                         W[(4 * k4 + 2) * OUTD + c], W[(4 * k4 + 3) * OUTD + c]);
  }
  __syncthreads();

  constexpr int RPG = TPB / OUTD;   // row groups per block
  constexpr int ROWS = RPG * RPT;   // rows per block
  const int col = t & (OUTD - 1);
  const int rg = t / OUTD;
  const int r0 = blockIdx.x * ROWS + rg * RPT;

  int rq[RPT];
#pragma unroll
  for (int q = 0; q < RPT; ++q) rq[q] = min(r0 + q, n - 1);

  const float a_s = avec_src[col];
  const float a_d = avec_dst[col];

  float acc[RPT];
#pragma unroll
  for (int q = 0; q < RPT; ++q) acc[q] = 0.f;

#pragma unroll 2
  for (int k4 = 0; k4 < K / 4; ++k4) {
    const float4 wv = ws4[k4 * OUTD + col];
#pragma unroll
    for (int q = 0; q < RPT; ++q) {
      const float4 xv =
          *(const float4*)(X + (size_t)rq[q] * K + 4 * k4);  // broadcast
      acc[q] = fmaf(xv.x, wv.x, acc[q]);
      acc[q] = fmaf(xv.y, wv.y, acc[q]);
      acc[q] = fmaf(xv.z, wv.z, acc[q]);
      acc[q] = fmaf(xv.w, wv.w, acc[q]);
    }
  }

#pragma unroll
  for (int q = 0; q < RPT; ++q) {
    const int r = r0 + q;
    if (r < n) {  // uniform within the OUTD-lane group
      Hout[(size_t)r * OUTD + col] = acc[q];
      float vs = acc[q] * a_s, vd = acc[q] * a_d;
#pragma unroll
      for (int m = OUTD / 2; m >= 1; m >>= 1) {
        vs += __shfl_xor(vs, m);
        vd += __shfl_xor(vd, m);
      }
      if (col == 0) {
        as_out[r] = vs;
        ad_out[r] = vd;
      }
    }
  }
}

// ---------------------------------------------------------------------------
// CSR-by-dst build: count -> 3-phase exclusive scan -> fill (stores SRC
// node id directly).
// ---------------------------------------------------------------------------
__global__ void count_edges(const int* __restrict__ edst, int E, int n,
                            int* __restrict__ cnt) {
  int i = blockIdx.x * blockDim.x + threadIdx.x;
  if (i >= E + n) return;
  int d = (i < E) ? edst[i] : (i - E);
  atomicAdd(&cnt[d], 1);
}

__global__ void scan_block_sums(const int* __restrict__ in, int n,
                                int* __restrict__ sums) {
  __shared__ int sdata[TPB];
  const int base = blockIdx.x * SCAN_CHUNK;
  int s = 0;
  for (int i = threadIdx.x; i < SCAN_CHUNK; i += TPB) {
    int idx = base + i;
    s += (idx < n) ? in[idx] : 0;
  }
  sdata[threadIdx.x] = s;
  __syncthreads();
  for (int m = TPB / 2; m >= 1; m >>= 1) {
    if (threadIdx.x < m) sdata[threadIdx.x] += sdata[threadIdx.x + m];
    __syncthreads();
  }
  if (threadIdx.x == 0) sums[blockIdx.x] = sdata[0];
}

__global__ void scan_sums_exclusive(int* __restrict__ sums, int nchunks,
                                    int* __restrict__ total) {
  if (blockIdx.x == 0 && threadIdx.x == 0) {
    int run = 0;
    for (int i = 0; i < nchunks; ++i) {
      int v = sums[i];
      sums[i] = run;
      run += v;
    }
    *total = run;
  }
}

__global__ void scan_write(const int* __restrict__ in, int n,
                           const int* __restrict__ chunkOff,
                           const int* __restrict__ total,
                           int* __restrict__ rowoff) {
  __shared__ int tsum[TPB];
  const int base = blockIdx.x * SCAN_CHUNK;
  const int t = threadIdx.x;
  int v[4];
  int s = 0;
#pragma unroll
  for (int j = 0; j < 4; ++j) {
    int idx = base + t * 4 + j;
    v[j] = (idx < n) ? in[idx] : 0;
    s += v[j];
  }
  tsum[t] = s;
  __syncthreads();
  for (int off = 1; off < TPB; off <<= 1) {  // Hillis-Steele inclusive
    int x = (t >= off) ? tsum[t - off] : 0;
    __syncthreads();
    tsum[t] += x;
    __syncthreads();
  }
  int excl = ((t == 0) ? 0 : tsum[t - 1]) + chunkOff[blockIdx.x];
#pragma unroll
  for (int j = 0; j < 4; ++j) {
    int idx = base + t * 4 + j;
    if (idx < n) rowoff[idx] = excl;
    excl += v[j];
  }
  if (blockIdx.x == 0 && t == 0) rowoff[n] = *total;
}

__global__ void fill_psrc(const int* __restrict__ esrc,
                          const int* __restrict__ edst, int E, int n,
                          int* __restrict__ cursor, int* __restrict__ psrc) {
  int i = blockIdx.x * blockDim.x + threadIdx.x;
  if (i >= E + n) return;
  int d, s;
  if (i < E) {
    d = edst[i];
    s = esrc[i];
  } else {
    d = i - E;
    s = i - E;
  }
  int pos = atomicAdd(&cursor[d], 1);
  psrc[pos] = s;
}

// ---------------------------------------------------------------------------
// GAT aggregation: one wave per destination node, single-pass online softmax.
// Per 64-edge chunk: lane l owns edge beg+c+l (parallel gathers of as[src]),
// wave-reduce chunk max & sum. The (w, src) pairs are parked in LDS as float2;
// the accumulation loop reads 1 pair per step per edge-phase (ds_read_b64
// broadcast) and gathers float2 of the H row: LPE = D/2 lanes per edge,
// EPS = 64/LPE edges per step (2 for D=64, 4 for D=32). Edge-phase partial
// sums are folded with shfl_xor at the end.
// ---------------------------------------------------------------------------
template <int D>
__global__ __launch_bounds__(TPB) void gat_aggregate(
    const float* __restrict__ Hf, const float* __restrict__ as,
    const float* __restrict__ ad, const int* __restrict__ rowoff,
    const int* __restrict__ psrc, int n, const float* __restrict__ bias,
    float* __restrict__ out, int doRelu) {
  constexpr int LPE = D / 2;      // lanes per edge (float2 each)
  constexpr int EPS = 64 / LPE;   // edges per step
  constexpr int WPB = TPB / 64;   // waves per block
  __shared__ float2 wsP[WPB][64];

  const int wave = (blockIdx.x * blockDim.x + threadIdx.x) >> 6;
  const int wid = threadIdx.x >> 6;
  const int lane = threadIdx.x & 63;
  if (wave >= n) return;
  const int i = wave;
  const int beg = rowoff[i];
  const int end = rowoff[i + 1];
  const float adi = ad[i];

  const int p = lane / LPE;            // edge phase within a step
  const int fl2 = (lane % LPE) * 2;    // feature pair base

  float m = -1e30f, denom = 0.f;
  float2 acc = make_float2(0.f, 0.f);

  for (int c = beg; c < end; c += 64) {
    const int k = c + lane;
    const bool valid = (k < end);
    int s = 0;
    float e = -1e30f;
    if (valid) {
      s = psrc[k];
      e = as[s] + adi;
      e = (e > 0.f) ? e : e * NEG_SLOPE;
    }
    // chunk max over the wave
    float cm = e;
#pragma unroll
    for (int mm = 32; mm >= 1; mm >>= 1) cm = fmaxf(cm, __shfl_xor(cm, mm));
    const float nm = fmaxf(m, cm);
    const float scale = __expf(m - nm);  // first chunk: exp(-inf) = 0
    const float w = valid ? __expf(e - nm) : 0.f;
    float ws = w;
#pragma unroll
    for (int mm = 32; mm >= 1; mm >>= 1) ws += __shfl_xor(ws, mm);
    denom = denom * scale + ws;
    acc.x *= scale;
    acc.y *= scale;
    m = nm;

    wsP[wid][lane] = make_float2(w, __int_as_float(s));  // park (w, src)

    const int cnt = min(64, end - c);
    const int nsteps = (cnt + EPS - 1) / EPS;
#pragma unroll 4
    for (int j = 0; j < nsteps; ++j) {
      const float2 p2 = wsP[wid][j * EPS + p];
      const float wj = p2.x;
      const int sj = __float_as_int(p2.y);
      const float2 hv = *(const float2*)(Hf + (size_t)sj * D + fl2);
      acc.x = fmaf(wj, hv.x, acc.x);
      acc.y = fmaf(wj, hv.y, acc.y);
    }
  }
  // fold edge-phase partials
#pragma unroll
  for (int mm = LPE; mm < 64; mm <<= 1) {
    acc.x += __shfl_xor(acc.x, mm);
    acc.y += __shfl_xor(acc.y, mm);
  }
  if (lane < LPE) {
    float2 o;
    o.x = acc.x / denom + bias[fl2];
    o.y = acc.y / denom + bias[fl2 + 1];
    if (doRelu) {
      o.x = fmaxf(o.x, 0.f);
      o.y = fmaxf(o.y, 0.f);
    }
    *(float2*)(out + (size_t)i * D + fl2) = o;
  }
}

// ---------------------------------------------------------------------------
// Decode: logits[g] = dot(z[src], z[dst]) over 32 dims.
// 8 lanes per edge, float4 per lane (coalesced 128B per row).
// ---------------------------------------------------------------------------
__global__ __launch_bounds__(TPB) void decode_kernel(
    const float* __restrict__ z, const int* __restrict__ pos,
    const int* __restrict__ neg, int ED, float* __restrict__ out) {
  const int g = (blockIdx.x * blockDim.x + threadIdx.x) >> 3;
  const int lane = threadIdx.x & 7;
  if (g >= 2 * ED) return;
  int s, d;
  if (g < ED) {
    s = pos[g];
    d = pos[ED + g];
  } else {
    s = neg[g - ED];
    d = neg[ED + (g - ED)];
  }
  const float4 a = ((const float4*)(z + (size_t)s * 32))[lane];
  const float4 b = ((const float4*)(z + (size_t)d * 32))[lane];
  float v = a.x * b.x + a.y * b.y + a.z * b.z + a.w * b.w;
#pragma unroll
  for (int mm = 4; mm >= 1; mm >>= 1) v += __shfl_xor(v, mm);
  if (lane == 0) out[g] = v;
}

// ---------------------------------------------------------------------------
extern "C" void kernel_launch(void* const* d_in, const int* in_sizes, int n_in,
                              void* d_out, int out_size, void* d_ws,
                              size_t ws_size, hipStream_t stream) {
  const int N = N_NODES;
  const float* x = (const float*)d_in[0];
  const int* ei = (const int*)d_in[1];
  const int* pe = (const int*)d_in[2];
  const int* ne = (const int*)d_in[3];
  const float* W1 = (const float*)d_in[4];
  const float* a_src1 = (const float*)d_in[5];
  const float* a_dst1 = (const float*)d_in[6];
  const float* b1 = (const float*)d_in[7];
  const float* W2 = (const float*)d_in[8];
  const float* a_src2 = (const float*)d_in[9];
  const float* a_dst2 = (const float*)d_in[10];
  const float* b2 = (const float*)d_in[11];
  float* out = (float*)d_out;

  const int E = in_sizes[1] / 2;
  const int ED = in_sizes[2] / 2;
  const int* esrc = ei;
  const int* edst = ei + E;

  // workspace carve-out (256B aligned)
  char* base = (char*)d_ws;
  size_t off = 0;
  auto alloc = [&](size_t bytes) {
    char* p = base + off;
    off = (off + bytes + 255) & ~(size_t)255;
    return p;
  };
  float* A = (float*)alloc((size_t)N * 64 * 4);  // h1, later h2
  float* B = (float*)alloc((size_t)N * 64 * 4);  // out1, later z
  float* as1 = (float*)alloc((size_t)N * 4);
  float* ad1 = (float*)alloc((size_t)N * 4);
  float* as2 = (float*)alloc((size_t)N * 4);
  float* ad2 = (float*)alloc((size_t)N * 4);
  int* cnt = (int*)alloc((size_t)N * 4);  // counts, then cursor
  int* rowoff = (int*)alloc((size_t)(N + 1) * 4);
  int* chunkSums = (int*)alloc(64 * 4);
  int* total = (int*)alloc(4);
  int* psrc = (int*)alloc((size_t)(E + N) * 4);

  const int nEdgesTot = E + N;
  const int edgeBlocks = (nEdgesTot + TPB - 1) / TPB;
  const int nchunks = (N + SCAN_CHUNK - 1) / SCAN_CHUNK;

  // --- CSR build (shared by both layers) ---
  hipMemsetAsync(cnt, 0, (size_t)N * 4, stream);
  count_edges<<<edgeBlocks, TPB, 0, stream>>>(edst, E, N, cnt);
  scan_block_sums<<<nchunks, TPB, 0, stream>>>(cnt, N, chunkSums);
  scan_sums_exclusive<<<1, 64, 0, stream>>>(chunkSums, nchunks, total);
  scan_write<<<nchunks, TPB, 0, stream>>>(cnt, N, chunkSums, total, rowoff);
  hipMemcpyAsync(cnt, rowoff, (size_t)N * 4, hipMemcpyDeviceToDevice, stream);
  fill_psrc<<<edgeBlocks, TPB, 0, stream>>>(esrc, edst, E, N, cnt, psrc);

  // --- layer 1: h1 = x@W1 (+alpha dots), aggregate (+b1, relu) ---
  gemm_alpha<128, 64, 4><<<(N + 15) / 16, TPB, 0, stream>>>(
      x, W1, a_src1, a_dst1, A, as1, ad1, N);
  gat_aggregate<64><<<(N + 3) / 4, TPB, 0, stream>>>(A, as1, ad1, rowoff, psrc,
                                                     N, b1, B, 1);

  // --- layer 2: h2 = out1@W2 (+alpha dots), aggregate (+b2) ---
  gemm_alpha<64, 32, 4><<<(N + 31) / 32, TPB, 0, stream>>>(
      B, W2, a_src2, a_dst2, A, as2, ad2, N);
  gat_aggregate<32><<<(N + 3) / 4, TPB, 0, stream>>>(A, as2, ad2, rowoff, psrc,
                                                     N, b2, B, 0);

  // --- decode ---
  const long long decThreads = 2LL * ED * 8;
  decode_kernel<<<(int)((decThreads + TPB - 1) / TPB), TPB, 0, stream>>>(
      B, pe, ne, ED, out);
}